// Round 1
// baseline (641.467 us; speedup 1.0000x reference)
//
#include <hip/hip_runtime.h>

// WassersteinLoss: per-row 1D W1 with uniform weights ==
//   (1/N) * sum_i |sort(u)[i] - sort(v)[i]|, then mean over rows.
// (The reference's merged-quantile construction collapses to this because
//  cumsum(1/4096) is exact in fp32: every dq is exactly 1/N, and the
//  duplicated quantile levels contribute delta == 0.)

constexpr int N_ELEM  = 4096;  // row length (fixed by the problem)
constexpr int THREADS = 256;

__global__ __launch_bounds__(THREADS) void w1_rows_kernel(
    const float* __restrict__ pred,
    const float* __restrict__ tru,
    float* __restrict__ out,
    float scale)
{
    __shared__ float su[N_ELEM];
    __shared__ float sv[N_ELEM];

    const int row = blockIdx.x;
    const size_t base = (size_t)row * N_ELEM;

    // Stage both rows into LDS with float4 loads (coalesced, 16B/lane).
    const float4* u4 = (const float4*)(pred + base);
    const float4* v4 = (const float4*)(tru + base);
    #pragma unroll
    for (int i = threadIdx.x; i < N_ELEM / 4; i += THREADS) {
        ((float4*)su)[i] = u4[i];
        ((float4*)sv)[i] = v4[i];
    }
    __syncthreads();

    // In-place bitonic sort (ascending) of both arrays simultaneously.
    // 12 stages, 78 passes total; each pass: 2048 disjoint pairs per array,
    // 8 pairs/thread/array with 256 threads.
    for (int size = 2; size <= N_ELEM; size <<= 1) {
        for (int stride = size >> 1; stride > 0; stride >>= 1) {
            #pragma unroll
            for (int w = 0; w < (N_ELEM / 2) / THREADS; ++w) {
                const int t = threadIdx.x + w * THREADS;
                const int i = ((t & ~(stride - 1)) << 1) | (t & (stride - 1));
                const int j = i + stride;
                const bool asc = ((i & size) == 0);

                float a = su[i], b = su[j];
                bool sw = (a > b) == asc;
                su[i] = sw ? b : a;
                su[j] = sw ? a : b;

                float c = sv[i], d = sv[j];
                bool sw2 = (c > d) == asc;
                sv[i] = sw2 ? d : c;
                sv[j] = sw2 ? c : d;
            }
            __syncthreads();
        }
    }

    // Row loss: sum_i |su[i] - sv[i]|  (scaled by 1/(N*B) on the atomic).
    float part = 0.f;
    #pragma unroll
    for (int i = threadIdx.x; i < N_ELEM; i += THREADS)
        part += fabsf(su[i] - sv[i]);

    // wave64 shuffle reduction
    #pragma unroll
    for (int off = 32; off > 0; off >>= 1)
        part += __shfl_down(part, off, 64);

    __shared__ float wsum[THREADS / 64];
    const int lane = threadIdx.x & 63;
    const int wid  = threadIdx.x >> 6;
    if (lane == 0) wsum[wid] = part;
    __syncthreads();
    if (threadIdx.x == 0) {
        float tot = 0.f;
        #pragma unroll
        for (int w = 0; w < THREADS / 64; ++w) tot += wsum[w];
        atomicAdd(out, tot * scale);
    }
}

extern "C" void kernel_launch(void* const* d_in, const int* in_sizes, int n_in,
                              void* d_out, int out_size, void* d_ws, size_t ws_size,
                              hipStream_t stream)
{
    (void)n_in; (void)out_size; (void)d_ws; (void)ws_size;

    const float* pred = (const float*)d_in[0];
    const float* tru  = (const float*)d_in[1];
    float* out = (float*)d_out;

    const int B = in_sizes[0] / N_ELEM;  // 4096 rows

    // Harness poisons d_out with 0xAA before every timed launch; zero it
    // ourselves (stream-ordered, graph-capturable).
    hipMemsetAsync(out, 0, sizeof(float), stream);

    const float scale = 1.0f / ((float)N_ELEM * (float)B);
    w1_rows_kernel<<<B, THREADS, 0, stream>>>(pred, tru, out, scale);
}

// Round 2
// 381.529 us; speedup vs baseline: 1.6813x; 1.6813x over previous
//
#include <hip/hip_runtime.h>

// WassersteinLoss: per-row W1 = (1/N) * sum_i |sort(u)[i] - sort(v)[i]|, mean over rows.
// R2: register-blocked bitonic sort. V=16 elems/thread/array (blocked layout).
//   - strides <=8 : in-register CE (42 of 78 passes, zero LDS)
//   - strides 16..512 : ds_bpermute intra-wave exchange (33 passes, no barriers)
//   - strides 1024/2048 : LDS round-trip, padded addr 17t+k (conflict-free), 3 passes
// R1 post-mortem: 78 all-LDS passes gave 1.05e8 bank-conflict cycles (~30% of kernel).

constexpr int N_ELEM  = 4096;
constexpr int THREADS = 256;
constexpr int V       = 16;                 // elements per thread per array
constexpr int BUF_SZ  = N_ELEM + N_ELEM / V; // 17 floats per 16 (pad) = 4352

// ---- in-register bitonic stages with compile-time direction (S = 2,4,8) ----
template<int S>
__device__ __forceinline__ void reg_stage_small(float r[V]) {
    #pragma unroll
    for (int s = S >> 1; s >= 1; s >>= 1) {
        #pragma unroll
        for (int k = 0; k < V; ++k) {
            if ((k & s) == 0) {
                const bool asc = ((k & S) == 0);
                float a = r[k], b = r[k + s];
                float lo = fminf(a, b), hi = fmaxf(a, b);
                r[k]     = asc ? lo : hi;
                r[k + s] = asc ? hi : lo;
            }
        }
    }
}

// ---- in-register strides 8,4,2,1 with runtime (thread-uniform) direction ----
__device__ __forceinline__ void reg_pass_dyn(float r[V], bool asc) {
    #pragma unroll
    for (int s = 8; s >= 1; s >>= 1) {
        #pragma unroll
        for (int k = 0; k < V; ++k) {
            if ((k & s) == 0) {
                float a = r[k], b = r[k + s];
                float lo = fminf(a, b), hi = fmaxf(a, b);
                r[k]     = asc ? lo : hi;
                r[k + s] = asc ? hi : lo;
            }
        }
    }
}

// ---- intra-wave cross-thread CE via ds_bpermute (lane xor m, m in 1..32) ----
__device__ __forceinline__ void shfl_pass2(float ru[V], float rv[V],
                                           int m, bool keep_min, int lane) {
    const int pa = (lane ^ m) << 2;  // byte index for ds_bpermute
    #pragma unroll
    for (int k = 0; k < V; ++k) {
        float ou = __int_as_float(
            __builtin_amdgcn_ds_bpermute(pa, __float_as_int(ru[k])));
        float ov = __int_as_float(
            __builtin_amdgcn_ds_bpermute(pa, __float_as_int(rv[k])));
        ru[k] = keep_min ? fminf(ru[k], ou) : fmaxf(ru[k], ou);
        rv[k] = keep_min ? fminf(rv[k], ov) : fmaxf(rv[k], ov);
    }
}

// ---- cross-wave CE through LDS (thread xor m = 64 or 128) ----
__device__ __forceinline__ void lds_pass(float r[V], float* buf,
                                         int t, int m, bool keep_min) {
    const int wbase = 17 * t;            // pad 1 per 16: conflict-free (17 odd)
    #pragma unroll
    for (int k = 0; k < V; ++k) buf[wbase + k] = r[k];
    __syncthreads();
    const int rbase = 17 * (t ^ m);
    #pragma unroll
    for (int k = 0; k < V; ++k) {
        float o = buf[rbase + k];
        r[k] = keep_min ? fminf(r[k], o) : fmaxf(r[k], o);
    }
    __syncthreads();
}

__global__ __launch_bounds__(THREADS) void w1_rows_kernel(
    const float* __restrict__ pred,
    const float* __restrict__ tru,
    float* __restrict__ out,
    float scale)
{
    __shared__ float buf[BUF_SZ];
    __shared__ float wsum[THREADS / 64];

    const int t    = threadIdx.x;
    const int lane = t & 63;
    const size_t base = (size_t)blockIdx.x * N_ELEM + (size_t)t * V;

    // Stage rows into registers, blocked layout: thread t owns g in [16t,16t+16).
    float ru[V], rv[V];
    {
        const float4* u4 = (const float4*)(pred + base);
        const float4* v4 = (const float4*)(tru  + base);
        #pragma unroll
        for (int c = 0; c < V / 4; ++c) {
            float4 a = u4[c], b = v4[c];
            ru[4*c+0] = a.x; ru[4*c+1] = a.y; ru[4*c+2] = a.z; ru[4*c+3] = a.w;
            rv[4*c+0] = b.x; rv[4*c+1] = b.y; rv[4*c+2] = b.z; rv[4*c+3] = b.w;
        }
    }

    // Phase 1: stages S=2,4,8 (compile-time dirs), stage S=16 (dir from t&1).
    reg_stage_small<2>(ru); reg_stage_small<2>(rv);
    reg_stage_small<4>(ru); reg_stage_small<4>(rv);
    reg_stage_small<8>(ru); reg_stage_small<8>(rv);
    {
        const bool asc16 = ((t & 1) == 0);
        reg_pass_dyn(ru, asc16); reg_pass_dyn(rv, asc16);
    }

    // Phase 2: stages S=32..4096.
    for (int S = 32; S <= N_ELEM; S <<= 1) {
        const bool asc = ((t & (S >> 4)) == 0);  // g&S == (t*16)&S for S>=32
        for (int s = S >> 1; s >= V; s >>= 1) {
            const int  m        = s >> 4;        // thread/lane xor distance
            const bool keep_min = (((t & m) == 0) == asc);
            if (m >= 64) {
                lds_pass(ru, buf, t, m, keep_min);
                lds_pass(rv, buf, t, m, keep_min);
            } else {
                shfl_pass2(ru, rv, m, keep_min, lane);
            }
        }
        reg_pass_dyn(ru, asc);
        reg_pass_dyn(rv, asc);
    }

    // Epilogue: sum |sorted_u - sorted_v| (indices align: same g per (t,k)).
    float part = 0.f;
    #pragma unroll
    for (int k = 0; k < V; ++k) part += fabsf(ru[k] - rv[k]);

    #pragma unroll
    for (int off = 32; off > 0; off >>= 1)
        part += __shfl_down(part, off, 64);

    const int wid = t >> 6;
    if (lane == 0) wsum[wid] = part;
    __syncthreads();
    if (t == 0) {
        float tot = 0.f;
        #pragma unroll
        for (int w = 0; w < THREADS / 64; ++w) tot += wsum[w];
        atomicAdd(out, tot * scale);
    }
}

extern "C" void kernel_launch(void* const* d_in, const int* in_sizes, int n_in,
                              void* d_out, int out_size, void* d_ws, size_t ws_size,
                              hipStream_t stream)
{
    (void)n_in; (void)out_size; (void)d_ws; (void)ws_size;

    const float* pred = (const float*)d_in[0];
    const float* tru  = (const float*)d_in[1];
    float* out = (float*)d_out;

    const int B = in_sizes[0] / N_ELEM;

    hipMemsetAsync(out, 0, sizeof(float), stream);

    const float scale = 1.0f / ((float)N_ELEM * (float)B);
    w1_rows_kernel<<<B, THREADS, 0, stream>>>(pred, tru, out, scale);
}